// Round 1
// baseline (342.705 us; speedup 1.0000x reference)
//
#include <hip/hip_runtime.h>

// Problem constants (from reference)
#define B_ 2048
#define S_ 200
#define D_ 128
#define H_ 64
#define ROWS (B_ * S_)        // 409600, divisible by 64
#define MASK_SCALE 1e10f

typedef __attribute__((ext_vector_type(8))) short short8_t;   // 8 bf16 in 4 VGPRs
typedef __attribute__((ext_vector_type(4))) float f32x4;

__device__ __forceinline__ short f2bf(float f) {
    unsigned u = __float_as_uint(f);
    unsigned r = (u + 0x7fffu + ((u >> 16) & 1u)) >> 16;   // round-to-nearest-even
    return (short)r;
}

// ---------------------------------------------------------------------------
// K0a: build Wh (=W1+W2) in bf16, pre-swizzled to MFMA B-fragment order, and
//      Wt (=W3-W2) in fp32.
// W is [3D, H] row-major. Fragment order for 16x16x32: B[k][n] with
// n = nt*16 + (lane&15), k = kt*32 + (lane>>4)*8 + j. Stored so lane loads
// 16 contiguous bytes: idx = ((kt*4+nt)*64 + lane)*8 + j.
// ---------------------------------------------------------------------------
__global__ __launch_bounds__(256) void prep_w(const float* __restrict__ W,
                                              float* __restrict__ wt,
                                              unsigned short* __restrict__ wfrag) {
    for (int idx = threadIdx.x; idx < D_ * H_; idx += 256) {
        int d = idx >> 6;          // 0..127
        int h = idx & 63;          // 0..63
        float w1 = W[d * H_ + h];
        float w2 = W[(D_ + d) * H_ + h];
        float w3 = W[(2 * D_ + d) * H_ + h];
        wt[idx] = w3 - w2;
        int kt = d >> 5, q = (d >> 3) & 3, j = d & 7;
        int nt = h >> 4, lm = h & 15;
        int lane = (q << 4) | lm;
        wfrag[((kt * 4 + nt) * 64 + lane) * 8 + j] = (unsigned short)f2bf(w1 + w2);
    }
}

// ---------------------------------------------------------------------------
// K0b: tproj[b][h] = W_bias[h] + sum_d target[b][d] * Wt[d][h]   (fp32)
// ---------------------------------------------------------------------------
__global__ __launch_bounds__(64) void prep_tproj(const float* __restrict__ target,
                                                 const float* __restrict__ W_bias,
                                                 const float* __restrict__ wt,
                                                 float* __restrict__ tproj) {
    int b = blockIdx.x;
    int h = threadIdx.x;
    float acc = W_bias[h];
    const float* tg = target + (size_t)b * D_;
    #pragma unroll 8
    for (int d = 0; d < D_; ++d)
        acc = fmaf(tg[d], wt[d * H_ + h], acc);
    tproj[b * H_ + h] = acc;
}

// ---------------------------------------------------------------------------
// K1: alpha[row] for all 409600 rows via bf16 MFMA 16x16x32.
// Each wave: 16 rows x 64 hidden, K=128 -> 16 MFMAs.
// A loaded from global (fp32 -> bf16 cvt in-reg), B fragments preloaded.
// Epilogue: +tproj, relu, dot O, quad reduce, -mask*1e10, store alpha.
// ---------------------------------------------------------------------------
__global__ __launch_bounds__(256) void alpha_kernel(const float* __restrict__ his,
                                                    const float* __restrict__ mask,
                                                    const unsigned short* __restrict__ wfrag,
                                                    const float* __restrict__ tproj,
                                                    const float* __restrict__ Ovec,
                                                    const float* __restrict__ O_bias,
                                                    float* __restrict__ alpha) {
    const int lane = threadIdx.x & 63;
    const int wv = threadIdx.x >> 6;
    const int tile = blockIdx.x * 4 + wv;
    const int row0 = tile * 16;
    const int lm = lane & 15;
    const int q = lane >> 4;

    // B fragments: 16 x 16B per lane, contiguous & coalesced
    short8_t bfrag[16];
    #pragma unroll
    for (int f = 0; f < 16; ++f)
        bfrag[f] = *(const short8_t*)(wfrag + ((size_t)(f * 64 + lane)) * 8);

    f32x4 acc[4];
    #pragma unroll
    for (int nt = 0; nt < 4; ++nt) acc[nt] = (f32x4){0.f, 0.f, 0.f, 0.f};

    const int arow = row0 + lm;                         // A row this lane supplies
    const float* hp = his + (size_t)arow * D_ + q * 8;  // k-offset of this quad

    #pragma unroll
    for (int kt = 0; kt < 4; ++kt) {
        float4 x0 = *(const float4*)(hp + kt * 32);
        float4 x1 = *(const float4*)(hp + kt * 32 + 4);
        short8_t a;
        a[0] = f2bf(x0.x); a[1] = f2bf(x0.y); a[2] = f2bf(x0.z); a[3] = f2bf(x0.w);
        a[4] = f2bf(x1.x); a[5] = f2bf(x1.y); a[6] = f2bf(x1.z); a[7] = f2bf(x1.w);
        #pragma unroll
        for (int nt = 0; nt < 4; ++nt)
            acc[nt] = __builtin_amdgcn_mfma_f32_16x16x32_bf16(a, bfrag[kt * 4 + nt], acc[nt], 0, 0, 0);
    }

    // Epilogue. C layout: col(n) = nt*16 + lm, row(m) = q*4 + r.
    float part[4];
    #pragma unroll
    for (int r = 0; r < 4; ++r) {
        int grow = row0 + q * 4 + r;
        int b = grow / S_;
        float sum = 0.f;
        #pragma unroll
        for (int nt = 0; nt < 4; ++nt) {
            int h = nt * 16 + lm;
            float v = acc[nt][r] + tproj[b * H_ + h];
            v = fmaxf(v, 0.f);
            sum = fmaf(v, Ovec[h], sum);
        }
        part[r] = sum;
    }
    // reduce across the 16 lanes of each quad
    #pragma unroll
    for (int off = 1; off < 16; off <<= 1) {
        #pragma unroll
        for (int r = 0; r < 4; ++r)
            part[r] += __shfl_xor(part[r], off);
    }
    if (lm == 0) {
        float ob = O_bias[0];
        #pragma unroll
        for (int r = 0; r < 4; ++r) {
            int grow = row0 + q * 4 + r;
            alpha[grow] = part[r] + ob - mask[grow] * MASK_SCALE;
        }
    }
}

// ---------------------------------------------------------------------------
// K2: per-batch softmax over alpha[b,0:200] then out[b,d] = sum_s w[s]*his[b,s,d]
// ---------------------------------------------------------------------------
__global__ __launch_bounds__(256) void pool_kernel(const float* __restrict__ his,
                                                   const float* __restrict__ alpha,
                                                   float* __restrict__ out) {
    __shared__ float sred[256];
    __shared__ float wgt[S_];
    __shared__ float partial[D_];

    const int b = blockIdx.x;
    const int t = threadIdx.x;

    float a = (t < S_) ? alpha[b * S_ + t] : -INFINITY;
    sred[t] = a;
    __syncthreads();
    #pragma unroll
    for (int s = 128; s > 0; s >>= 1) {
        if (t < s) sred[t] = fmaxf(sred[t], sred[t + s]);
        __syncthreads();
    }
    float m = sred[0];
    __syncthreads();
    float e = (t < S_) ? expf(a - m) : 0.f;
    sred[t] = e;
    __syncthreads();
    #pragma unroll
    for (int s = 128; s > 0; s >>= 1) {
        if (t < s) sred[t] += sred[t + s];
        __syncthreads();
    }
    float inv = 1.f / sred[0];
    if (t < S_) wgt[t] = e * inv;
    __syncthreads();

    const int d = t & 127;
    const int half = t >> 7;                 // 0 or 1 -> s in [0,100) or [100,200)
    const float* hb = his + (size_t)b * S_ * D_ + (size_t)half * 100 * D_ + d;
    float accv = 0.f;
    #pragma unroll 4
    for (int s = 0; s < 100; ++s)
        accv = fmaf(wgt[half * 100 + s], hb[(size_t)s * D_], accv);

    if (half) partial[d] = accv;
    __syncthreads();
    if (!half) out[b * D_ + d] = accv + partial[d];
}

// ---------------------------------------------------------------------------
extern "C" void kernel_launch(void* const* d_in, const int* in_sizes, int n_in,
                              void* d_out, int out_size, void* d_ws, size_t ws_size,
                              hipStream_t stream) {
    const float* his    = (const float*)d_in[0];
    const float* target = (const float*)d_in[1];
    const float* mask   = (const float*)d_in[2];
    const float* W      = (const float*)d_in[3];
    const float* W_bias = (const float*)d_in[4];
    const float* Ovec   = (const float*)d_in[5];
    const float* O_bias = (const float*)d_in[6];
    float* out = (float*)d_out;

    // workspace layout (needs ~2.2 MB)
    char* ws = (char*)d_ws;
    float* wt             = (float*)(ws);                        // 8192 f  (32 KB)
    unsigned short* wfrag = (unsigned short*)(ws + 32768);       // 8192 us (16 KB)
    float* tproj          = (float*)(ws + 65536);                // B*H f   (512 KB)
    float* alpha          = (float*)(ws + 65536 + 524288);       // B*S f   (1.6 MB)

    prep_w<<<1, 256, 0, stream>>>(W, wt, wfrag);
    prep_tproj<<<B_, 64, 0, stream>>>(target, W_bias, wt, tproj);
    alpha_kernel<<<ROWS / 64, 256, 0, stream>>>(his, mask, wfrag, tproj, Ovec, O_bias, alpha);
    pool_kernel<<<B_, 256, 0, stream>>>(his, alpha, out);
}

// Round 2
// 328.242 us; speedup vs baseline: 1.0441x; 1.0441x over previous
//
#include <hip/hip_runtime.h>

// Problem constants (from reference)
#define B_ 2048
#define S_ 200
#define D_ 128
#define H_ 64
#define MASK_SCALE 1e10f
#define LSTRIDE 136              // bf16 elems per LDS row: 128 + 8 pad (16B-aligned rows, 4-bank shift/row)

typedef __attribute__((ext_vector_type(8))) short short8_t;            // 8 bf16 in 4 VGPRs
typedef __attribute__((ext_vector_type(4))) float f32x4;
typedef __attribute__((ext_vector_type(4))) unsigned short ushort4_t;  // 8B

__device__ __forceinline__ unsigned short f2bf(float f) {
    unsigned u = __float_as_uint(f);
    unsigned r = (u + 0x7fffu + ((u >> 16) & 1u)) >> 16;   // round-to-nearest-even
    return (unsigned short)r;
}
__device__ __forceinline__ float bf2f(unsigned short v) {
    return __uint_as_float(((unsigned)v) << 16);
}

// ---------------------------------------------------------------------------
// K0a: build Wh (=W1+W2) in bf16, pre-swizzled to MFMA B-fragment order, and
//      Wt (=W3-W2) in fp32.  (W is [3D,H] row-major; 16x16x32 B-frag:
//      n = nt*16+(lane&15), k = kt*32+(lane>>4)*8+j; stored so each lane
//      loads 16 contiguous bytes.)
// ---------------------------------------------------------------------------
__global__ __launch_bounds__(256) void prep_w(const float* __restrict__ W,
                                              float* __restrict__ wt,
                                              unsigned short* __restrict__ wfrag) {
    for (int idx = threadIdx.x; idx < D_ * H_; idx += 256) {
        int d = idx >> 6;          // 0..127
        int h = idx & 63;          // 0..63
        float w1 = W[d * H_ + h];
        float w2 = W[(D_ + d) * H_ + h];
        float w3 = W[(2 * D_ + d) * H_ + h];
        wt[idx] = w3 - w2;
        int kt = d >> 5, q = (d >> 3) & 3, j = d & 7;
        int nt = h >> 4, lm = h & 15;
        int lane = (q << 4) | lm;
        wfrag[((kt * 4 + nt) * 64 + lane) * 8 + j] = f2bf(w1 + w2);
    }
}

// ---------------------------------------------------------------------------
// K0b: tproj[b][h] = W_bias[h] + sum_d target[b][d] * Wt[d][h]   (fp32)
// ---------------------------------------------------------------------------
__global__ __launch_bounds__(64) void prep_tproj(const float* __restrict__ target,
                                                 const float* __restrict__ W_bias,
                                                 const float* __restrict__ wt,
                                                 float* __restrict__ tproj) {
    int b = blockIdx.x;
    int h = threadIdx.x;
    float acc = W_bias[h];
    const float* tg = target + (size_t)b * D_;
    #pragma unroll 8
    for (int d = 0; d < D_; ++d)
        acc = fmaf(tg[d], wt[d * H_ + h], acc);
    tproj[b * H_ + h] = acc;
}

// ---------------------------------------------------------------------------
// Fused: one block per batch. Stage his[b] -> LDS bf16 (single coalesced HBM
// pass), MFMA alpha, block softmax, weighted pool from LDS.
// ---------------------------------------------------------------------------
__global__ __launch_bounds__(256, 2) void fused_kernel(const float* __restrict__ his,
                                                       const float* __restrict__ mask,
                                                       const unsigned short* __restrict__ wfrag,
                                                       const float* __restrict__ tproj,
                                                       const float* __restrict__ Ovec,
                                                       float* __restrict__ out) {
    __shared__ unsigned short hisb[S_ * LSTRIDE];   // 54,400 B
    __shared__ float alpha_s[208];                  // 13 tiles x 16 rows (pad rows 200..207)
    __shared__ float red8[8];
    __shared__ float tp_s[H_];
    __shared__ float ov_s[H_];
    __shared__ float pool_s[3 * D_];                // partials for s-groups 1..3

    const int b    = blockIdx.x;
    const int t    = threadIdx.x;
    const int lane = t & 63;
    const int wv   = t >> 6;
    const int lm   = lane & 15;
    const int q    = lane >> 4;

    // B fragments: 16 x 16B per lane (same for every block -> L2 broadcast)
    short8_t bfrag[16];
    #pragma unroll
    for (int f = 0; f < 16; ++f)
        bfrag[f] = *(const short8_t*)(wfrag + ((size_t)(f * 64 + lane)) * 8);

    if (t < H_) {
        tp_s[t] = tproj[b * H_ + t];
        ov_s[t] = Ovec[t];
    }

    // ---- stage his[b] -> LDS bf16 (25 fully-coalesced float4 loads/thread) ----
    const float4* hb4 = (const float4*)(his + (size_t)b * S_ * D_);
    #pragma unroll
    for (int i = t, it = 0; it < (S_ * D_ / 4 + 255) / 256; ++it, i += 256) {
        if (i < S_ * D_ / 4) {
            float4 x = hb4[i];
            int s  = i >> 5;       // 32 float4 per row
            int d4 = i & 31;
            ushort4_t v;
            v[0] = f2bf(x.x); v[1] = f2bf(x.y); v[2] = f2bf(x.z); v[3] = f2bf(x.w);
            *(ushort4_t*)(&hisb[s * LSTRIDE + d4 * 4]) = v;
        }
    }
    __syncthreads();

    // ---- alpha via MFMA: 13 tiles of 16 rows, round-robin over 4 waves ----
    for (int tile = wv; tile < 13; tile += 4) {
        int row0 = tile * 16;
        int ar = row0 + lm; if (ar > S_ - 1) ar = S_ - 1;   // clamp pad rows
        const unsigned short* ap = &hisb[ar * LSTRIDE + q * 8];

        f32x4 acc[4];
        #pragma unroll
        for (int nt = 0; nt < 4; ++nt) acc[nt] = (f32x4){0.f, 0.f, 0.f, 0.f};

        #pragma unroll
        for (int kt = 0; kt < 4; ++kt) {
            short8_t a = *(const short8_t*)(ap + kt * 32);
            #pragma unroll
            for (int nt = 0; nt < 4; ++nt)
                acc[nt] = __builtin_amdgcn_mfma_f32_16x16x32_bf16(a, bfrag[kt * 4 + nt], acc[nt], 0, 0, 0);
        }

        // epilogue: +tproj, relu, dot O (O_bias is softmax-invariant -> skipped)
        float part[4];
        #pragma unroll
        for (int r = 0; r < 4; ++r) {
            float sum = 0.f;
            #pragma unroll
            for (int nt = 0; nt < 4; ++nt) {
                int h = nt * 16 + lm;
                float v = acc[nt][r] + tp_s[h];
                v = fmaxf(v, 0.f);
                sum = fmaf(v, ov_s[h], sum);
            }
            part[r] = sum;
        }
        #pragma unroll
        for (int off = 1; off < 16; off <<= 1) {
            #pragma unroll
            for (int r = 0; r < 4; ++r)
                part[r] += __shfl_xor(part[r], off);
        }
        if (lm == 0) {
            #pragma unroll
            for (int r = 0; r < 4; ++r)
                alpha_s[row0 + q * 4 + r] = part[r];
        }
    }
    __syncthreads();

    // ---- block softmax over s = 0..199 ----
    float a = (t < S_) ? alpha_s[t] - mask[(size_t)b * S_ + t] * MASK_SCALE : -INFINITY;
    float m = a;
    #pragma unroll
    for (int off = 1; off < 64; off <<= 1) m = fmaxf(m, __shfl_xor(m, off));
    if (lane == 0) red8[wv] = m;
    __syncthreads();
    m = fmaxf(fmaxf(red8[0], red8[1]), fmaxf(red8[2], red8[3]));
    float e = (t < S_) ? __expf(a - m) : 0.f;
    float ssum = e;
    #pragma unroll
    for (int off = 1; off < 64; off <<= 1) ssum += __shfl_xor(ssum, off);
    if (lane == 0) red8[4 + wv] = ssum;
    __syncthreads();
    float inv = 1.f / (red8[4] + red8[5] + red8[6] + red8[7]);
    __syncthreads();                 // alpha_s reads done before overwrite below
    if (t < S_) alpha_s[t] = e * inv;
    __syncthreads();

    // ---- pooling: out[b][d] = sum_s w[s] * his_bf[s][d] ----
    const int d2 = t & 63;           // word index; d = 2*d2
    const int sg = t >> 6;           // 0..3 s-groups
    float ax = 0.f, ay = 0.f;
    for (int s = sg; s < S_; s += 4) {
        float w = alpha_s[s];        // broadcast (same addr per wave)
        unsigned v = *(const unsigned*)(&hisb[s * LSTRIDE + d2 * 2]);
        ax = fmaf(w, bf2f((unsigned short)(v & 0xffff)), ax);
        ay = fmaf(w, bf2f((unsigned short)(v >> 16)), ay);
    }
    if (sg) {
        pool_s[(sg - 1) * D_ + d2 * 2]     = ax;
        pool_s[(sg - 1) * D_ + d2 * 2 + 1] = ay;
    }
    __syncthreads();
    if (sg == 0) {
        #pragma unroll
        for (int k = 0; k < 3; ++k) {
            ax += pool_s[k * D_ + d2 * 2];
            ay += pool_s[k * D_ + d2 * 2 + 1];
        }
        float2 o; o.x = ax; o.y = ay;
        ((float2*)out)[b * (D_ / 2) + d2] = o;
    }
}

// ---------------------------------------------------------------------------
extern "C" void kernel_launch(void* const* d_in, const int* in_sizes, int n_in,
                              void* d_out, int out_size, void* d_ws, size_t ws_size,
                              hipStream_t stream) {
    const float* his    = (const float*)d_in[0];
    const float* target = (const float*)d_in[1];
    const float* mask   = (const float*)d_in[2];
    const float* W      = (const float*)d_in[3];
    const float* W_bias = (const float*)d_in[4];
    const float* Ovec   = (const float*)d_in[5];
    // O_bias (d_in[6]) is softmax-invariant -> unused
    float* out = (float*)d_out;

    char* ws = (char*)d_ws;
    float* wt             = (float*)(ws);                  // 8192 f  (32 KB)
    unsigned short* wfrag = (unsigned short*)(ws + 32768); // 8192 us (16 KB)
    float* tproj          = (float*)(ws + 65536);          // B*H f   (512 KB)

    prep_w<<<1, 256, 0, stream>>>(W, wt, wfrag);
    prep_tproj<<<B_, 64, 0, stream>>>(target, W_bias, wt, tproj);
    fused_kernel<<<B_, 256, 0, stream>>>(his, mask, wfrag, tproj, Ovec, out);
}